// Round 1
// baseline (8991.537 us; speedup 1.0000x reference)
//
#include <hip/hip_runtime.h>
#include <hip/hip_bf16.h>

#define NB   65536
#define HID  512
#define MID  256
#define PROJ 128
#define KNEG 8

#define BM 32
#define KB 32
#define TEMP_INV (1.0f/0.07f)

// ---------------------------------------------------------------------------
// Kernel A: pool[2B][128] = L2norm( LN( relu(X@W1+b1) @ W2 + b2 )*g + beta )
// ---------------------------------------------------------------------------
__global__ __launch_bounds__(256, 3)
void proj_kernel(const float* __restrict__ hs, const float* __restrict__ ph,
                 const float* __restrict__ W1, const float* __restrict__ b1,
                 const float* __restrict__ W2, const float* __restrict__ b2,
                 const float* __restrict__ gam, const float* __restrict__ bet,
                 float* __restrict__ pool)
{
    __shared__ float lds[12288];          // 48 KB
    float* AsT = lds;                     // phase1: [KB][BM]   (transposed A tile)
    float* Bs  = lds + 1024;              // phase1: [KB][MID]
    float* HsT = lds;                     // phase2: [MID][BM]  swizzled (reuses phase1 space)
    float* W2s = lds + 8192;              // phase2: [KB][PROJ]

    const int tid = threadIdx.x;
    const int tm  = tid >> 5;             // 0..7   -> rows tm*4..+4
    const int tn  = tid & 31;             // 0..31  -> cols tn*8..+8 (GEMM1) / tn*4..+4 (GEMM2)
    const int row0 = blockIdx.x * BM;
    const float* __restrict__ X = (row0 < NB) ? (hs + (size_t)row0 * HID)
                                              : (ph + (size_t)(row0 - NB) * HID);

    // bias fragment for GEMM1 epilogue
    float4 b1a = *reinterpret_cast<const float4*>(b1 + tn*8);
    float4 b1b = *reinterpret_cast<const float4*>(b1 + tn*8 + 4);
    float b1f[8] = {b1a.x,b1a.y,b1a.z,b1a.w,b1b.x,b1b.y,b1b.z,b1b.w};

    float acc[4][8];
    #pragma unroll
    for (int i=0;i<4;i++)
        #pragma unroll
        for (int j=0;j<8;j++) acc[i][j] = 0.f;

    const int a_r  = tid >> 3;            // 0..31
    const int a_kq = tid & 7;             // 0..7

    float4 pa;
    float4 pb[8];

    auto load1 = [&](int k0) {
        pa = *reinterpret_cast<const float4*>(X + a_r*HID + k0 + a_kq*4);
        #pragma unroll
        for (int i=0;i<8;i++) {
            int f  = i*256 + tid;
            int k  = f >> 6;
            int c4 = f & 63;
            pb[i] = *reinterpret_cast<const float4*>(W1 + (size_t)(k0 + k)*MID + c4*4);
        }
    };
    auto write1 = [&]() {
        AsT[(a_kq*4+0)*BM + a_r] = pa.x;
        AsT[(a_kq*4+1)*BM + a_r] = pa.y;
        AsT[(a_kq*4+2)*BM + a_r] = pa.z;
        AsT[(a_kq*4+3)*BM + a_r] = pa.w;
        #pragma unroll
        for (int i=0;i<8;i++) {
            int f  = i*256 + tid;
            int k  = f >> 6;
            int c4 = f & 63;
            *reinterpret_cast<float4*>(Bs + k*MID + c4*4) = pb[i];
        }
    };

    // -------- phase 1: GEMM1 (X[32][512] @ W1[512][256]) --------
    load1(0);
    write1();
    __syncthreads();

    for (int t = 0; t < HID/KB; ++t) {
        if (t+1 < HID/KB) load1((t+1)*KB);
        #pragma unroll
        for (int kk=0; kk<KB; ++kk) {
            float4 a = *reinterpret_cast<const float4*>(AsT + kk*BM + tm*4);
            float4 u = *reinterpret_cast<const float4*>(Bs + kk*MID + tn*8);
            float4 v = *reinterpret_cast<const float4*>(Bs + kk*MID + tn*8 + 4);
            float av[4] = {a.x,a.y,a.z,a.w};
            float bv[8] = {u.x,u.y,u.z,u.w,v.x,v.y,v.z,v.w};
            #pragma unroll
            for (int i=0;i<4;i++)
                #pragma unroll
                for (int j=0;j<8;j++)
                    acc[i][j] = fmaf(av[i], bv[j], acc[i][j]);
        }
        __syncthreads();
        if (t+1 < HID/KB) write1();
        __syncthreads();
    }

    // epilogue: relu(acc+b1) -> HsT, XOR-swizzled so phase-2 column reads are
    // contiguous b128 and bank-spread. element (r,kk) stored at HsT[kk*BM + (r ^ cw)]
    {
        const int cw = (tn & 7) << 2;     // == ((kk>>3)&7)<<2 for kk = tn*8+j, j<8
        #pragma unroll
        for (int j=0;j<8;j++) {
            const int kk = tn*8 + j;
            #pragma unroll
            for (int i=0;i<4;i++) {
                float h = fmaxf(acc[i][j] + b1f[j], 0.f);
                HsT[kk*BM + ((tm*4 + i) ^ cw)] = h;
            }
        }
    }
    __syncthreads();

    // -------- phase 2: GEMM2 (H[32][256] @ W2[256][128]) --------
    float4 g4  = *reinterpret_cast<const float4*>(gam + tn*4);
    float4 be4 = *reinterpret_cast<const float4*>(bet + tn*4);
    float4 b24 = *reinterpret_cast<const float4*>(b2  + tn*4);
    float gf[4]  = {g4.x,g4.y,g4.z,g4.w};
    float bf[4]  = {be4.x,be4.y,be4.z,be4.w};
    float b2f[4] = {b24.x,b24.y,b24.z,b24.w};

    float acc2[4][4];
    #pragma unroll
    for (int i=0;i<4;i++)
        #pragma unroll
        for (int j=0;j<4;j++) acc2[i][j] = 0.f;

    float4 qb[4];
    auto load2 = [&](int k20) {
        #pragma unroll
        for (int i=0;i<4;i++) {
            int f  = i*256 + tid;
            int k  = f >> 5;
            int c4 = f & 31;
            qb[i] = *reinterpret_cast<const float4*>(W2 + (size_t)(k20 + k)*PROJ + c4*4);
        }
    };
    auto write2 = [&]() {
        #pragma unroll
        for (int i=0;i<4;i++) {
            int f  = i*256 + tid;
            int k  = f >> 5;
            int c4 = f & 31;
            *reinterpret_cast<float4*>(W2s + k*PROJ + c4*4) = qb[i];
        }
    };

    load2(0);
    write2();
    __syncthreads();

    for (int t = 0; t < MID/KB; ++t) {
        if (t+1 < MID/KB) load2((t+1)*KB);
        const int kbase = t*KB;
        #pragma unroll
        for (int kk=0; kk<KB; ++kk) {
            const int kkg = kbase + kk;
            const int c = ((kkg >> 3) & 7) << 2;
            float4 a = *reinterpret_cast<const float4*>(HsT + kkg*BM + ((tm*4) ^ c));
            float4 w = *reinterpret_cast<const float4*>(W2s + kk*PROJ + tn*4);
            float av[4] = {a.x,a.y,a.z,a.w};
            float wv[4] = {w.x,w.y,w.z,w.w};
            #pragma unroll
            for (int i=0;i<4;i++)
                #pragma unroll
                for (int j=0;j<4;j++)
                    acc2[i][j] = fmaf(av[i], wv[j], acc2[i][j]);
        }
        __syncthreads();
        if (t+1 < MID/KB) write2();
        __syncthreads();
    }

    // -------- LN + L2 normalize + store --------
    // row (tm*4+i) owned by the 32 threads sharing tm (a half-wave): reduce via shfl_xor
    #pragma unroll
    for (int i=0;i<4;i++) {
        float v[4];
        float lsum = 0.f, lsq = 0.f;
        #pragma unroll
        for (int j=0;j<4;j++) {
            v[j] = acc2[i][j] + b2f[j];
            lsum += v[j];
            lsq  += v[j]*v[j];
        }
        #pragma unroll
        for (int m=1;m<32;m<<=1) {
            lsum += __shfl_xor(lsum, m, 64);
            lsq  += __shfl_xor(lsq,  m, 64);
        }
        float mu   = lsum * (1.0f/PROJ);
        float var  = lsq  * (1.0f/PROJ) - mu*mu;
        float rstd = rsqrtf(var + 1e-5f);
        float l2 = 0.f;
        #pragma unroll
        for (int j=0;j<4;j++) {
            v[j] = (v[j]-mu)*rstd*gf[j] + bf[j];
            l2 += v[j]*v[j];
        }
        #pragma unroll
        for (int m=1;m<32;m<<=1) l2 += __shfl_xor(l2, m, 64);
        float rn = rsqrtf(l2);
        float4 o;
        o.x = v[0]*rn; o.y = v[1]*rn; o.z = v[2]*rn; o.w = v[3]*rn;
        *reinterpret_cast<float4*>(pool + (size_t)(row0 + tm*4 + i)*PROJ + tn*4) = o;
    }
}

// ---------------------------------------------------------------------------
// Kernel B: per-row InfoNCE loss -> per-block partial sums
// ---------------------------------------------------------------------------
__global__ __launch_bounds__(256, 4)
void loss_kernel(const float* __restrict__ pool, const int* __restrict__ nidx,
                 float* __restrict__ partials)
{
    const int wave = threadIdx.x >> 6;
    const int lane = threadIdx.x & 63;
    float local = 0.f;

    for (int b = blockIdx.x*4 + wave; b < NB; b += gridDim.x*4) {
        const float2 av = *reinterpret_cast<const float2*>(pool + (size_t)b*PROJ + lane*2);
        const float2 pv = *reinterpret_cast<const float2*>(pool + (size_t)(b + NB)*PROJ + lane*2);
        float d[9];
        d[0] = av.x*pv.x + av.y*pv.y;
        #pragma unroll
        for (int k=0;k<KNEG;k++) {
            const int idx = nidx[b*KNEG + k];
            const float2 nv = *reinterpret_cast<const float2*>(pool + (size_t)idx*PROJ + lane*2);
            d[k+1] = av.x*nv.x + av.y*nv.y;
        }
        #pragma unroll
        for (int m=1;m<64;m<<=1)
            #pragma unroll
            for (int t=0;t<9;t++) d[t] += __shfl_xor(d[t], m, 64);

        float pos = d[0]*TEMP_INV;
        float mx = pos;
        #pragma unroll
        for (int t=1;t<9;t++) mx = fmaxf(mx, d[t]*TEMP_INV);
        float se = 0.f;
        #pragma unroll
        for (int t=0;t<9;t++) se += __expf(d[t]*TEMP_INV - mx);
        float loss = -pos + mx + __logf(se);
        if (lane == 0) local += loss;
    }

    __shared__ float red[4];
    if (lane == 0) red[wave] = local;
    __syncthreads();
    if (threadIdx.x == 0)
        partials[blockIdx.x] = red[0]+red[1]+red[2]+red[3];
}

// ---------------------------------------------------------------------------
// Kernel C: final reduction -> mean
// ---------------------------------------------------------------------------
__global__ __launch_bounds__(256)
void reduce_kernel(const float* __restrict__ partials, float* __restrict__ out)
{
    const int tid = threadIdx.x;
    float s = 0.f;
    for (int i = tid; i < 4096; i += 256) s += partials[i];
    #pragma unroll
    for (int m=1;m<64;m<<=1) s += __shfl_xor(s, m, 64);
    __shared__ float red[4];
    if ((tid & 63) == 0) red[tid >> 6] = s;
    __syncthreads();
    if (tid == 0)
        out[0] = (red[0]+red[1]+red[2]+red[3]) * (1.0f/NB);
}

// ---------------------------------------------------------------------------
extern "C" void kernel_launch(void* const* d_in, const int* in_sizes, int n_in,
                              void* d_out, int out_size, void* d_ws, size_t ws_size,
                              hipStream_t stream)
{
    const float* hs = (const float*)d_in[0];
    const float* ph = (const float*)d_in[1];
    const int*   ni = (const int*)  d_in[2];
    const float* W1 = (const float*)d_in[3];
    const float* b1 = (const float*)d_in[4];
    const float* W2 = (const float*)d_in[5];
    const float* b2 = (const float*)d_in[6];
    const float* gm = (const float*)d_in[7];
    const float* bt = (const float*)d_in[8];

    float* pool     = (float*)d_ws;                       // 2B*128 floats = 64 MiB
    float* partials = pool + (size_t)2*NB*PROJ;           // 4096 floats
    float* out      = (float*)d_out;

    proj_kernel<<<2*NB/BM, 256, 0, stream>>>(hs, ph, W1, b1, W2, b2, gm, bt, pool);
    loss_kernel<<<4096, 256, 0, stream>>>(pool, ni, partials);
    reduce_kernel<<<1, 256, 0, stream>>>(partials, out);
}

// Round 6
// 929.171 us; speedup vs baseline: 9.6770x; 9.6770x over previous
//
#include <hip/hip_runtime.h>
#include <hip/hip_bf16.h>

#define NB   65536
#define HID  512
#define MID  256
#define PROJ 128
#define KNEG 8
#define TEMP_INV (1.0f/0.07f)

#define BM 32
#define KB 32

// ---------------------------------------------------------------------------
// Fused projection: pool[2B][128] = L2norm( LN( relu(X@W1+b1) @ W2 + b2 ) )
// Structure: stage -> barrier -> compute (NO register state live across
// barriers -> no spill). H tile persists in LDS between the two GEMMs.
// ---------------------------------------------------------------------------
__global__ __launch_bounds__(256, 2)
void proj_kernel(const float* __restrict__ hs, const float* __restrict__ ph,
                 const float* __restrict__ W1, const float* __restrict__ b1,
                 const float* __restrict__ W2, const float* __restrict__ b2,
                 const float* __restrict__ gam, const float* __restrict__ bet,
                 float* __restrict__ pool)
{
    __shared__ float Hs[BM * MID];        // 32 KB, persistent H tile
    __shared__ float Sb[9216];            // 36 KB: As(1024) + Bs(8192); W2s reuses
    float* As  = Sb;                      // [32][32]  row-major
    float* Bs  = Sb + 1024;               // [32][256] row-major
    float* W2s = Sb;                      // [32][128] row-major (phase 2 reuse)

    const int tid = threadIdx.x;
    const int tm  = tid >> 5;             // 0..7  -> rows tm*4..+4
    const int tn  = tid & 31;             // 0..31 -> cols tn*4 (+128)
    const int wv  = tid >> 6;             // wave id 0..3
    const int ln  = tid & 63;             // lane
    const int row0 = blockIdx.x * BM;
    const float* __restrict__ X = (row0 < NB) ? (hs + (size_t)row0 * HID)
                                              : (ph + (size_t)(row0 - NB) * HID);

    // -------- phase 1: acc1 = X[32][512] @ W1[512][256] --------
    float acc1[4][8];
    #pragma unroll
    for (int i = 0; i < 4; i++)
        #pragma unroll
        for (int j = 0; j < 8; j++) acc1[i][j] = 0.f;

    const int sr = tid >> 3;              // As stage: row 0..31
    const int sc = (tid & 7) * 4;         //           col group

    for (int t = 0; t < HID / KB; ++t) {
        const int k0 = t * KB;
        __syncthreads();                  // previous tile's compute done
        // stage As[32][32]: one float4 per thread
        *reinterpret_cast<float4*>(As + sr * KB + sc) =
            *reinterpret_cast<const float4*>(X + (size_t)sr * HID + k0 + sc);
        // stage Bs[32][256]: one wave-row (256 floats) per (wave,i)
        #pragma unroll
        for (int i = 0; i < 8; i++) {
            const int r = i * 4 + wv;
            *reinterpret_cast<float4*>(Bs + r * MID + ln * 4) =
                *reinterpret_cast<const float4*>(W1 + (size_t)(k0 + r) * MID + ln * 4);
        }
        __syncthreads();                  // tile staged
        #pragma unroll
        for (int kk = 0; kk < KB; ++kk) {
            // A fragment: scalar broadcast reads (2 distinct addrs/wave)
            float a0 = As[(tm * 4 + 0) * KB + kk];
            float a1 = As[(tm * 4 + 1) * KB + kk];
            float a2 = As[(tm * 4 + 2) * KB + kk];
            float a3 = As[(tm * 4 + 3) * KB + kk];
            // B fragment: interleaved cols tn*4 and 128+tn*4
            float4 u = *reinterpret_cast<const float4*>(Bs + kk * MID + tn * 4);
            float4 v = *reinterpret_cast<const float4*>(Bs + kk * MID + 128 + tn * 4);
            float av[4] = {a0, a1, a2, a3};
            float bv[8] = {u.x, u.y, u.z, u.w, v.x, v.y, v.z, v.w};
            #pragma unroll
            for (int i = 0; i < 4; i++)
                #pragma unroll
                for (int j = 0; j < 8; j++)
                    acc1[i][j] = fmaf(av[i], bv[j], acc1[i][j]);
        }
    }

    // -------- epilogue 1: H = relu(acc1 + b1) -> LDS (row-major) --------
    {
        float4 bh0 = *reinterpret_cast<const float4*>(b1 + tn * 4);
        float4 bh1 = *reinterpret_cast<const float4*>(b1 + 128 + tn * 4);
        #pragma unroll
        for (int i = 0; i < 4; i++) {
            float4 h0, h1;
            h0.x = fmaxf(acc1[i][0] + bh0.x, 0.f);
            h0.y = fmaxf(acc1[i][1] + bh0.y, 0.f);
            h0.z = fmaxf(acc1[i][2] + bh0.z, 0.f);
            h0.w = fmaxf(acc1[i][3] + bh0.w, 0.f);
            h1.x = fmaxf(acc1[i][4] + bh1.x, 0.f);
            h1.y = fmaxf(acc1[i][5] + bh1.y, 0.f);
            h1.z = fmaxf(acc1[i][6] + bh1.z, 0.f);
            h1.w = fmaxf(acc1[i][7] + bh1.w, 0.f);
            *reinterpret_cast<float4*>(Hs + (tm * 4 + i) * MID + tn * 4) = h0;
            *reinterpret_cast<float4*>(Hs + (tm * 4 + i) * MID + 128 + tn * 4) = h1;
        }
    }

    // -------- phase 2: acc2 = H[32][256] @ W2[256][128] --------
    float acc2[4][4];
    #pragma unroll
    for (int i = 0; i < 4; i++)
        #pragma unroll
        for (int j = 0; j < 4; j++) acc2[i][j] = 0.f;

    for (int t2 = 0; t2 < MID / KB; ++t2) {
        const int k20 = t2 * KB;
        __syncthreads();   // t2=0: H writes + phase-1 reads of Sb complete
        #pragma unroll
        for (int i = 0; i < 4; i++) {
            const int r = i * 8 + tm;
            *reinterpret_cast<float4*>(W2s + r * PROJ + tn * 4) =
                *reinterpret_cast<const float4*>(W2 + (size_t)(k20 + r) * PROJ + tn * 4);
        }
        __syncthreads();
        #pragma unroll
        for (int kk = 0; kk < KB; ++kk) {
            const int k2 = k20 + kk;
            float a0 = Hs[(tm * 4 + 0) * MID + k2];
            float a1 = Hs[(tm * 4 + 1) * MID + k2];
            float a2 = Hs[(tm * 4 + 2) * MID + k2];
            float a3 = Hs[(tm * 4 + 3) * MID + k2];
            float4 w = *reinterpret_cast<const float4*>(W2s + kk * PROJ + tn * 4);
            float av[4] = {a0, a1, a2, a3};
            float wv4[4] = {w.x, w.y, w.z, w.w};
            #pragma unroll
            for (int i = 0; i < 4; i++)
                #pragma unroll
                for (int j = 0; j < 4; j++)
                    acc2[i][j] = fmaf(av[i], wv4[j], acc2[i][j]);
        }
    }

    // -------- epilogue 2: bias + LN + L2 normalize + store --------
    {
        float4 g4  = *reinterpret_cast<const float4*>(gam + tn * 4);
        float4 be4 = *reinterpret_cast<const float4*>(bet + tn * 4);
        float4 b24 = *reinterpret_cast<const float4*>(b2  + tn * 4);
        float gf[4]  = {g4.x, g4.y, g4.z, g4.w};
        float bf[4]  = {be4.x, be4.y, be4.z, be4.w};
        float b2f[4] = {b24.x, b24.y, b24.z, b24.w};

        #pragma unroll
        for (int i = 0; i < 4; i++) {
            float v[4];
            float lsum = 0.f, lsq = 0.f;
            #pragma unroll
            for (int j = 0; j < 4; j++) {
                v[j] = acc2[i][j] + b2f[j];
                lsum += v[j];
                lsq  += v[j] * v[j];
            }
            #pragma unroll
            for (int m = 1; m < 32; m <<= 1) {
                lsum += __shfl_xor(lsum, m, 64);
                lsq  += __shfl_xor(lsq,  m, 64);
            }
            float mu   = lsum * (1.0f / PROJ);
            float var  = lsq  * (1.0f / PROJ) - mu * mu;
            float rstd = rsqrtf(var + 1e-5f);
            float l2 = 0.f;
            #pragma unroll
            for (int j = 0; j < 4; j++) {
                v[j] = (v[j] - mu) * rstd * gf[j] + bf[j];
                l2 += v[j] * v[j];
            }
            #pragma unroll
            for (int m = 1; m < 32; m <<= 1) l2 += __shfl_xor(l2, m, 64);
            float rn = rsqrtf(l2);
            float4 o;
            o.x = v[0] * rn; o.y = v[1] * rn; o.z = v[2] * rn; o.w = v[3] * rn;
            *reinterpret_cast<float4*>(pool + (size_t)(row0 + tm * 4 + i) * PROJ + tn * 4) = o;
        }
    }
}

// ---------------------------------------------------------------------------
// Kernel B: per-row InfoNCE loss -> per-block partial sums
// ---------------------------------------------------------------------------
__global__ __launch_bounds__(256, 4)
void loss_kernel(const float* __restrict__ pool, const int* __restrict__ nidx,
                 float* __restrict__ partials)
{
    const int wave = threadIdx.x >> 6;
    const int lane = threadIdx.x & 63;
    float local = 0.f;

    for (int b = blockIdx.x * 4 + wave; b < NB; b += gridDim.x * 4) {
        const float2 av = *reinterpret_cast<const float2*>(pool + (size_t)b * PROJ + lane * 2);
        const float2 pv = *reinterpret_cast<const float2*>(pool + (size_t)(b + NB) * PROJ + lane * 2);
        float d[9];
        d[0] = av.x * pv.x + av.y * pv.y;
        #pragma unroll
        for (int k = 0; k < KNEG; k++) {
            const int idx = nidx[b * KNEG + k];
            const float2 nv = *reinterpret_cast<const float2*>(pool + (size_t)idx * PROJ + lane * 2);
            d[k + 1] = av.x * nv.x + av.y * nv.y;
        }
        #pragma unroll
        for (int m = 1; m < 64; m <<= 1)
            #pragma unroll
            for (int t = 0; t < 9; t++) d[t] += __shfl_xor(d[t], m, 64);

        float pos = d[0] * TEMP_INV;
        float mx = pos;
        #pragma unroll
        for (int t = 1; t < 9; t++) mx = fmaxf(mx, d[t] * TEMP_INV);
        float se = 0.f;
        #pragma unroll
        for (int t = 0; t < 9; t++) se += __expf(d[t] * TEMP_INV - mx);
        float loss = -pos + mx + __logf(se);
        if (lane == 0) local += loss;
    }

    __shared__ float red[4];
    if (lane == 0) red[wave] = local;
    __syncthreads();
    if (threadIdx.x == 0)
        partials[blockIdx.x] = red[0] + red[1] + red[2] + red[3];
}

// ---------------------------------------------------------------------------
// Kernel C: final reduction -> mean
// ---------------------------------------------------------------------------
__global__ __launch_bounds__(256)
void reduce_kernel(const float* __restrict__ partials, float* __restrict__ out)
{
    const int tid = threadIdx.x;
    float s = 0.f;
    for (int i = tid; i < 4096; i += 256) s += partials[i];
    #pragma unroll
    for (int m = 1; m < 64; m <<= 1) s += __shfl_xor(s, m, 64);
    __shared__ float red[4];
    if ((tid & 63) == 0) red[tid >> 6] = s;
    __syncthreads();
    if (tid == 0)
        out[0] = (red[0] + red[1] + red[2] + red[3]) * (1.0f / NB);
}

// ---------------------------------------------------------------------------
extern "C" void kernel_launch(void* const* d_in, const int* in_sizes, int n_in,
                              void* d_out, int out_size, void* d_ws, size_t ws_size,
                              hipStream_t stream)
{
    const float* hs = (const float*)d_in[0];
    const float* ph = (const float*)d_in[1];
    const int*   ni = (const int*)  d_in[2];
    const float* W1 = (const float*)d_in[3];
    const float* b1 = (const float*)d_in[4];
    const float* W2 = (const float*)d_in[5];
    const float* b2 = (const float*)d_in[6];
    const float* gm = (const float*)d_in[7];
    const float* bt = (const float*)d_in[8];

    float* pool     = (float*)d_ws;                 // 2B*128 floats = 67 MB
    float* partials = pool + (size_t)2 * NB * PROJ; // 4096 floats
    float* out      = (float*)d_out;

    proj_kernel<<<2 * NB / BM, 256, 0, stream>>>(hs, ph, W1, b1, W2, b2, gm, bt, pool);
    loss_kernel<<<4096, 256, 0, stream>>>(pool, ni, partials);
    reduce_kernel<<<1, 256, 0, stream>>>(partials, out);
}

// Round 7
// 636.047 us; speedup vs baseline: 14.1366x; 1.4609x over previous
//
#include <hip/hip_runtime.h>

#define NB   65536
#define HID  512
#define MID  256
#define PROJ 128
#define KNEG 8
#define TEMP_INV (1.0f/0.07f)

typedef __attribute__((ext_vector_type(8))) short bf16x8;
typedef __attribute__((ext_vector_type(4))) float f32x4;

#define A_STR 520   // 32 rows x 520 shorts (pad +8 -> conflict-free b128 frag reads)
#define H_STR 264   // 32 rows x 264 shorts
#define P_STR 132   // 32 rows x 132 floats

__device__ __forceinline__ short f2bf(float x) {
    unsigned u = __float_as_uint(x);
    unsigned r = (u + 0x7fffu + ((u >> 16) & 1u)) >> 16;   // RNE
    return (short)r;
}
__device__ __forceinline__ float bf2f(short h) {
    return __uint_as_float(((unsigned)(unsigned short)h) << 16);
}

// ---------------------------------------------------------------------------
// Weight prep: W [K][N] fp32 -> WT hi/lo bf16 [N][K] (K-contiguous)
// ---------------------------------------------------------------------------
__global__ void prep_w_kernel(const float* __restrict__ W, short* __restrict__ hi,
                              short* __restrict__ lo, int N, int Kshift, int total)
{
    int idx = blockIdx.x * 256 + threadIdx.x;
    if (idx >= total) return;
    int n = idx >> Kshift;
    int k = idx & ((1 << Kshift) - 1);
    float x = W[(size_t)k * N + n];
    short h = f2bf(x);
    short l = f2bf(x - bf2f(h));
    hi[idx] = h;
    lo[idx] = l;
}

// ---------------------------------------------------------------------------
// Fused projection via MFMA bf16x3 (hi*hi + hi*lo + lo*hi)
// pool[2B][128] = L2norm( LN( relu(X@W1+b1) @ W2 + b2 ) )
// ---------------------------------------------------------------------------
__global__ __launch_bounds__(256, 2)
void proj_mfma(const float* __restrict__ hs, const float* __restrict__ ph,
               const short* __restrict__ w1h, const short* __restrict__ w1l,
               const short* __restrict__ w2h, const short* __restrict__ w2l,
               const float* __restrict__ b1, const float* __restrict__ b2,
               const float* __restrict__ gam, const float* __restrict__ bet,
               float* __restrict__ pool)
{
    __shared__ float smem[16640];               // 66,560 B
    short* Ahi = (short*)smem;                  // [32][520]  (33,280 B)
    short* Alo = Ahi + 32 * A_STR;              // [32][520]
    short* Hhi = (short*)smem;                  // [32][264]  (overlays A after barrier)
    short* Hlo = Hhi + 32 * H_STR;
    float* P   = smem + (32 * H_STR);           // float idx 8448 = byte 33,792 (past H)

    const int tid  = threadIdx.x;
    const int w    = tid >> 6;                  // wave 0..3
    const int lane = tid & 63;
    const int l16  = lane & 15;
    const int g    = lane >> 4;                 // 0..3
    const int row0 = blockIdx.x * 32;
    const float* __restrict__ X = (row0 < NB) ? (hs + (size_t)row0 * HID)
                                              : (ph + (size_t)(row0 - NB) * HID);

    // -------- stage & split X tile [32][512] -> Ahi/Alo --------
    #pragma unroll
    for (int i = 0; i < 16; ++i) {
        const int f = i * 1024 + tid * 4;       // = r*512 + c
        const int r = f >> 9, c = f & 511;
        float4 v = *reinterpret_cast<const float4*>(X + f);
        float xv[4] = {v.x, v.y, v.z, v.w};
        short hh[4], ll[4];
        #pragma unroll
        for (int j = 0; j < 4; ++j) {
            hh[j] = f2bf(xv[j]);
            ll[j] = f2bf(xv[j] - bf2f(hh[j]));
        }
        *reinterpret_cast<short4*>(Ahi + r * A_STR + c) = make_short4(hh[0], hh[1], hh[2], hh[3]);
        *reinterpret_cast<short4*>(Alo + r * A_STR + c) = make_short4(ll[0], ll[1], ll[2], ll[3]);
    }

    // b1 fragment (col = w*64 + nb*16 + l16)
    float b1v[4];
    #pragma unroll
    for (int nb = 0; nb < 4; ++nb) b1v[nb] = b1[w * 64 + nb * 16 + l16];

    __syncthreads();

    // -------- GEMM1: [32][512] @ W1T[256][512] -> acc[2 Mblk][4 Nblk] --------
    f32x4 acc[2][4];
    #pragma unroll
    for (int mb = 0; mb < 2; ++mb)
        #pragma unroll
        for (int nb = 0; nb < 4; ++nb) acc[mb][nb] = (f32x4){0.f, 0.f, 0.f, 0.f};

    const int koff = g * 8;
    for (int t = 0; t < 16; ++t) {
        const int k0 = t * 32 + koff;
        bf16x8 a_h[2], a_l[2], b_h[4], b_l[4];
        #pragma unroll
        for (int mb = 0; mb < 2; ++mb) {
            const int ro = (mb * 16 + l16) * A_STR + k0;
            a_h[mb] = *reinterpret_cast<const bf16x8*>(Ahi + ro);
            a_l[mb] = *reinterpret_cast<const bf16x8*>(Alo + ro);
        }
        #pragma unroll
        for (int nb = 0; nb < 4; ++nb) {
            const size_t co = (size_t)(w * 64 + nb * 16 + l16) * 512 + k0;
            b_h[nb] = *reinterpret_cast<const bf16x8*>(w1h + co);
            b_l[nb] = *reinterpret_cast<const bf16x8*>(w1l + co);
        }
        #pragma unroll
        for (int mb = 0; mb < 2; ++mb)
            #pragma unroll
            for (int nb = 0; nb < 4; ++nb) {
                acc[mb][nb] = __builtin_amdgcn_mfma_f32_16x16x32_bf16(a_h[mb], b_h[nb], acc[mb][nb], 0, 0, 0);
                acc[mb][nb] = __builtin_amdgcn_mfma_f32_16x16x32_bf16(a_h[mb], b_l[nb], acc[mb][nb], 0, 0, 0);
                acc[mb][nb] = __builtin_amdgcn_mfma_f32_16x16x32_bf16(a_l[mb], b_h[nb], acc[mb][nb], 0, 0, 0);
            }
    }

    __syncthreads();   // all GEMM1 A-reads done; A region can be overwritten

    // -------- H = relu(acc + b1) -> Hhi/Hlo (C/D: col=lane&15, row=g*4+reg) --------
    #pragma unroll
    for (int mb = 0; mb < 2; ++mb)
        #pragma unroll
        for (int nb = 0; nb < 4; ++nb) {
            const int col = w * 64 + nb * 16 + l16;
            #pragma unroll
            for (int r = 0; r < 4; ++r) {
                const int row = mb * 16 + g * 4 + r;
                float hval = fmaxf(acc[mb][nb][r] + b1v[nb], 0.f);
                short hh = f2bf(hval);
                short hl = f2bf(hval - bf2f(hh));
                Hhi[row * H_STR + col] = hh;
                Hlo[row * H_STR + col] = hl;
            }
        }

    __syncthreads();

    // -------- GEMM2: H[32][256] @ W2T[128][256] -> acc2[2][2] --------
    f32x4 acc2[2][2];
    #pragma unroll
    for (int mb = 0; mb < 2; ++mb)
        #pragma unroll
        for (int nb = 0; nb < 2; ++nb) acc2[mb][nb] = (f32x4){0.f, 0.f, 0.f, 0.f};

    for (int t = 0; t < 8; ++t) {
        const int k0 = t * 32 + koff;
        bf16x8 a_h[2], a_l[2], b_h[2], b_l[2];
        #pragma unroll
        for (int mb = 0; mb < 2; ++mb) {
            const int ro = (mb * 16 + l16) * H_STR + k0;
            a_h[mb] = *reinterpret_cast<const bf16x8*>(Hhi + ro);
            a_l[mb] = *reinterpret_cast<const bf16x8*>(Hlo + ro);
        }
        #pragma unroll
        for (int nb = 0; nb < 2; ++nb) {
            const size_t co = (size_t)(w * 32 + nb * 16 + l16) * 256 + k0;
            b_h[nb] = *reinterpret_cast<const bf16x8*>(w2h + co);
            b_l[nb] = *reinterpret_cast<const bf16x8*>(w2l + co);
        }
        #pragma unroll
        for (int mb = 0; mb < 2; ++mb)
            #pragma unroll
            for (int nb = 0; nb < 2; ++nb) {
                acc2[mb][nb] = __builtin_amdgcn_mfma_f32_16x16x32_bf16(a_h[mb], b_h[nb], acc2[mb][nb], 0, 0, 0);
                acc2[mb][nb] = __builtin_amdgcn_mfma_f32_16x16x32_bf16(a_h[mb], b_l[nb], acc2[mb][nb], 0, 0, 0);
                acc2[mb][nb] = __builtin_amdgcn_mfma_f32_16x16x32_bf16(a_l[mb], b_h[nb], acc2[mb][nb], 0, 0, 0);
            }
    }

    // -------- P -> LDS (region disjoint from H; no barrier needed before) --------
    #pragma unroll
    for (int mb = 0; mb < 2; ++mb)
        #pragma unroll
        for (int nb = 0; nb < 2; ++nb) {
            const int col = w * 32 + nb * 16 + l16;
            #pragma unroll
            for (int r = 0; r < 4; ++r) {
                const int row = mb * 16 + g * 4 + r;
                P[row * P_STR + col] = acc2[mb][nb][r];
            }
        }

    __syncthreads();

    // -------- bias + LN + L2 normalize + store (verified epilogue) --------
    {
        const int tm = tid >> 5;               // rows tm*4..+4
        const int tn = tid & 31;               // cols tn*4
        float4 g4  = *reinterpret_cast<const float4*>(gam + tn * 4);
        float4 be4 = *reinterpret_cast<const float4*>(bet + tn * 4);
        float4 b24 = *reinterpret_cast<const float4*>(b2  + tn * 4);
        float gf[4]  = {g4.x, g4.y, g4.z, g4.w};
        float bf[4]  = {be4.x, be4.y, be4.z, be4.w};
        float b2f[4] = {b24.x, b24.y, b24.z, b24.w};

        #pragma unroll
        for (int i = 0; i < 4; ++i) {
            float4 pv = *reinterpret_cast<const float4*>(P + (tm * 4 + i) * P_STR + tn * 4);
            float v[4] = {pv.x, pv.y, pv.z, pv.w};
            float lsum = 0.f, lsq = 0.f;
            #pragma unroll
            for (int j = 0; j < 4; ++j) {
                v[j] += b2f[j];
                lsum += v[j];
                lsq  += v[j] * v[j];
            }
            #pragma unroll
            for (int m = 1; m < 32; m <<= 1) {
                lsum += __shfl_xor(lsum, m, 64);
                lsq  += __shfl_xor(lsq,  m, 64);
            }
            float mu   = lsum * (1.0f / PROJ);
            float var  = lsq  * (1.0f / PROJ) - mu * mu;
            float rstd = rsqrtf(var + 1e-5f);
            float l2 = 0.f;
            #pragma unroll
            for (int j = 0; j < 4; ++j) {
                v[j] = (v[j] - mu) * rstd * gf[j] + bf[j];
                l2 += v[j] * v[j];
            }
            #pragma unroll
            for (int m = 1; m < 32; m <<= 1) l2 += __shfl_xor(l2, m, 64);
            float rn = rsqrtf(l2);
            float4 o;
            o.x = v[0] * rn; o.y = v[1] * rn; o.z = v[2] * rn; o.w = v[3] * rn;
            *reinterpret_cast<float4*>(pool + (size_t)(row0 + tm * 4 + i) * PROJ + tn * 4) = o;
        }
    }
}

// ---------------------------------------------------------------------------
// Kernel B: per-row InfoNCE loss -> per-block partial sums
// ---------------------------------------------------------------------------
__global__ __launch_bounds__(256, 4)
void loss_kernel(const float* __restrict__ pool, const int* __restrict__ nidx,
                 float* __restrict__ partials)
{
    const int wave = threadIdx.x >> 6;
    const int lane = threadIdx.x & 63;
    float local = 0.f;

    for (int b = blockIdx.x * 4 + wave; b < NB; b += gridDim.x * 4) {
        const float2 av = *reinterpret_cast<const float2*>(pool + (size_t)b * PROJ + lane * 2);
        const float2 pv = *reinterpret_cast<const float2*>(pool + (size_t)(b + NB) * PROJ + lane * 2);
        float d[9];
        d[0] = av.x * pv.x + av.y * pv.y;
        #pragma unroll
        for (int k = 0; k < KNEG; k++) {
            const int idx = nidx[b * KNEG + k];
            const float2 nv = *reinterpret_cast<const float2*>(pool + (size_t)idx * PROJ + lane * 2);
            d[k + 1] = av.x * nv.x + av.y * nv.y;
        }
        #pragma unroll
        for (int m = 1; m < 64; m <<= 1)
            #pragma unroll
            for (int t = 0; t < 9; t++) d[t] += __shfl_xor(d[t], m, 64);

        float pos = d[0] * TEMP_INV;
        float mx = pos;
        #pragma unroll
        for (int t = 1; t < 9; t++) mx = fmaxf(mx, d[t] * TEMP_INV);
        float se = 0.f;
        #pragma unroll
        for (int t = 0; t < 9; t++) se += __expf(d[t] * TEMP_INV - mx);
        float loss = -pos + mx + __logf(se);
        if (lane == 0) local += loss;
    }

    __shared__ float red[4];
    if (lane == 0) red[wave] = local;
    __syncthreads();
    if (threadIdx.x == 0)
        partials[blockIdx.x] = red[0] + red[1] + red[2] + red[3];
}

// ---------------------------------------------------------------------------
// Kernel C: final reduction -> mean
// ---------------------------------------------------------------------------
__global__ __launch_bounds__(256)
void reduce_kernel(const float* __restrict__ partials, float* __restrict__ out)
{
    const int tid = threadIdx.x;
    float s = 0.f;
    for (int i = tid; i < 4096; i += 256) s += partials[i];
    #pragma unroll
    for (int m = 1; m < 64; m <<= 1) s += __shfl_xor(s, m, 64);
    __shared__ float red[4];
    if ((tid & 63) == 0) red[tid >> 6] = s;
    __syncthreads();
    if (tid == 0)
        out[0] = (red[0] + red[1] + red[2] + red[3]) * (1.0f / NB);
}

// ---------------------------------------------------------------------------
extern "C" void kernel_launch(void* const* d_in, const int* in_sizes, int n_in,
                              void* d_out, int out_size, void* d_ws, size_t ws_size,
                              hipStream_t stream)
{
    const float* hs = (const float*)d_in[0];
    const float* ph = (const float*)d_in[1];
    const int*   ni = (const int*)  d_in[2];
    const float* W1 = (const float*)d_in[3];
    const float* b1 = (const float*)d_in[4];
    const float* W2 = (const float*)d_in[5];
    const float* b2 = (const float*)d_in[6];
    const float* gm = (const float*)d_in[7];
    const float* bt = (const float*)d_in[8];

    float* pool     = (float*)d_ws;                 // 2B*128 f32 = 67.1 MB
    float* partials = pool + (size_t)2 * NB * PROJ; // 4096 f32
    short* w1h = (short*)(partials + 4096);         // [256][512] bf16
    short* w1l = w1h + HID * MID;                   // 131072 shorts each
    short* w2h = w1l + HID * MID;                   // [128][256] bf16
    short* w2l = w2h + MID * PROJ;
    float* out = (float*)d_out;

    // weight transpose+split (recomputed every call; ws is re-poisoned)
    prep_w_kernel<<<(HID * MID + 255) / 256, 256, 0, stream>>>(W1, w1h, w1l, MID, 9, HID * MID);
    prep_w_kernel<<<(MID * PROJ + 255) / 256, 256, 0, stream>>>(W2, w2h, w2l, PROJ, 8, MID * PROJ);

    proj_mfma<<<2 * NB / 32, 256, 0, stream>>>(hs, ph, w1h, w1l, w2h, w2l, b1, b2, gm, bt, pool);
    loss_kernel<<<4096, 256, 0, stream>>>(pool, ni, partials);
    reduce_kernel<<<1, 256, 0, stream>>>(partials, out);
}